// Round 4
// baseline (298.768 us; speedup 1.0000x reference)
//
#include <hip/hip_runtime.h>
#include <hip/hip_bf16.h>
#include <cstdint>

// Problem constants
#define TOK   64
#define INF   4096
#define OUTF  11008
#define KCHUNKS 128      // INF / 32
#define QCNT  16         // split-K factor
#define KC    8          // k32-chunks per block (K_block = 256)
#define NBLK2 86         // OUTF / 128 channels per block

using bf16x8  = __attribute__((ext_vector_type(8))) __bf16;
using floatx4 = __attribute__((ext_vector_type(4))) float;

union B8u { uint32_t u[4]; uint4 q; bf16x8 v; };

// pack two fp32 into one dword of two truncated bf16 (elem a = low half)
__device__ __forceinline__ uint32_t hi2(float a, float b) {
    return (__float_as_uint(a) >> 16) | (__float_as_uint(b) & 0xffff0000u);
}
// residual after bf16 truncation (exact in fp32)
__device__ __forceinline__ float losub(float x) {
    return x - __uint_as_float(__float_as_uint(x) & 0xffff0000u);
}
__device__ __forceinline__ void packW(float4 a, float4 b, B8u& wh, B8u& wl) {
    wh.u[0] = hi2(a.x, a.y);  wh.u[1] = hi2(a.z, a.w);
    wh.u[2] = hi2(b.x, b.y);  wh.u[3] = hi2(b.z, b.w);
    wl.u[0] = hi2(losub(a.x), losub(a.y));
    wl.u[1] = hi2(losub(a.z), losub(a.w));
    wl.u[2] = hi2(losub(b.x), losub(b.y));
    wl.u[3] = hi2(losub(b.z), losub(b.w));
}

// ---------------------------------------------------------------------------
// k_prep_x: fp32 x[64][4096] -> bf16 hi/lo arrays in MFMA A-fragment order.
// uint4 index = (mt*128 + kc)*64 + lane ; elem j: x[mt*16+(lane&15)][kc*32+(lane>>4)*8+j]
// ---------------------------------------------------------------------------
__global__ __launch_bounds__(256) void k_prep_x(const float* __restrict__ x,
        unsigned short* __restrict__ xh, unsigned short* __restrict__ xl) {
    int idx  = blockIdx.x * 256 + threadIdx.x;          // 0..262143
    int j    = idx & 7;
    int lane = (idx >> 3) & 63;
    int kc   = (idx >> 9) & 127;
    int mt   = idx >> 16;
    int row  = mt * 16 + (lane & 15);
    int col  = kc * 32 + ((lane >> 4) << 3) + j;
    float v  = x[(size_t)row * INF + col];
    uint32_t u = __float_as_uint(v);
    float lo = losub(v);
    xh[idx] = (unsigned short)(u >> 16);
    xl[idx] = (unsigned short)(__float_as_uint(lo) >> 16);
}

// ---------------------------------------------------------------------------
// k_lora_t: tm[t][r] = sum_k x[t][k] * A[r][k].  grid (64 tokens, 4 rgroups),
// one wave per (t,r); fully unrolled -> independent loads in flight.
// ---------------------------------------------------------------------------
__global__ __launch_bounds__(256) void k_lora_t(const float* __restrict__ x,
        const float* __restrict__ A, float* __restrict__ tm) {
    int t = blockIdx.x, wv = threadIdx.x >> 6, lane = threadIdx.x & 63;
    int r = blockIdx.y * 4 + wv;
    const float4* xr = (const float4*)(x + (size_t)t * INF);
    const float4* ar = (const float4*)(A + (size_t)r * INF);
    float s = 0.f;
#pragma unroll
    for (int i = 0; i < INF / 4 / 64; ++i) {
        float4 a = xr[lane + i * 64], b = ar[lane + i * 64];
        s += a.x * b.x + a.y * b.y + a.z * b.z + a.w * b.w;
    }
#pragma unroll
    for (int off = 32; off > 0; off >>= 1) s += __shfl_down(s, off);
    if (lane == 0) tm[t * 16 + r] = s;
}

// ---------------------------------------------------------------------------
// k_main: y = x @ W^T via 16x16x32 bf16 MFMA, fp32 emulated hi/lo:
//   x*w ~= xh*wh + xh*wl + xl*wh
// Restructured K-loop: x staged ONCE per block into 64KB LDS via
// global_load_lds (single barrier, only x drained); W ring (32 dwordx4/lane)
// issued AFTER the barrier so no barrier ever drains it -- compute consumes
// it with compiler fine-grained vmcnt waits. Block = 128 channels x 64 tok.
// ---------------------------------------------------------------------------
template<bool ATOMIC>
__global__ __launch_bounds__(256, 2) void k_main(const float* __restrict__ W,
        const uint4* __restrict__ xh, const uint4* __restrict__ xl,
        const float* __restrict__ scale, float* __restrict__ part,
        float* __restrict__ out) {
    __shared__ uint4 xs[2][4][KC][64];   // 64 KB: [hi/lo][mt][kc][lane]

    int tid  = threadIdx.x;
    int lane = tid & 63;
    int wv   = tid >> 6;
    int nb   = blockIdx.x % NBLK2;
    int q    = blockIdx.x / NBLK2;       // 0..QCNT-1
    int quad = lane >> 4;
    int ch0  = nb * 128 + wv * 32 + (lane & 15);   // tile0 channel; tile1 = +16

    // ---- stage x fragments into LDS (once). 64 chunks of 1KB; 16 per wave.
#pragma unroll
    for (int i = 0; i < 16; ++i) {
        int c  = wv * 16 + i;            // 0..63, wave-uniform base per chunk
        int hl = c >> 5, mt = (c >> 3) & 3, kc = c & 7;
        const uint4* g = (hl ? xl : xh)
                       + ((size_t)mt * KCHUNKS + q * KC + kc) * 64 + lane;
        __builtin_amdgcn_global_load_lds(
            (const __attribute__((address_space(1))) uint32_t*)g,
            (__attribute__((address_space(3))) uint32_t*)&xs[hl][mt][kc][0],
            16, 0, 0);
    }
    __syncthreads();   // drains only the x stage (W not yet issued)

    // ---- issue the full W ring: 2 channel tiles x 8 kc x 2 float4 per lane
    const float* wp0 = W + (size_t)ch0 * INF + q * (KC * 32) + quad * 8;
    const float* wp1 = wp0 + (size_t)16 * INF;
    float4 w0a[KC], w0b[KC], w1a[KC], w1b[KC];
#pragma unroll
    for (int kc = 0; kc < KC; ++kc) {
        w0a[kc] = *(const float4*)(wp0 + kc * 32);
        w0b[kc] = *(const float4*)(wp0 + kc * 32 + 4);
        w1a[kc] = *(const float4*)(wp1 + kc * 32);
        w1b[kc] = *(const float4*)(wp1 + kc * 32 + 4);
    }

    floatx4 acc0[4] = {}, acc1[4] = {};

    // ---- compute: per kc the pack+MFMA waits only on that kc's 4 loads
#pragma unroll
    for (int kc = 0; kc < KC; ++kc) {
        B8u wh0, wl0, wh1, wl1;
        packW(w0a[kc], w0b[kc], wh0, wl0);
        packW(w1a[kc], w1b[kc], wh1, wl1);
#pragma unroll
        for (int mt = 0; mt < 4; ++mt) {
            B8u ah, al;
            ah.q = xs[0][mt][kc][lane];
            al.q = xs[1][mt][kc][lane];
            acc0[mt] = __builtin_amdgcn_mfma_f32_16x16x32_bf16(ah.v, wh0.v, acc0[mt], 0, 0, 0);
            acc0[mt] = __builtin_amdgcn_mfma_f32_16x16x32_bf16(ah.v, wl0.v, acc0[mt], 0, 0, 0);
            acc0[mt] = __builtin_amdgcn_mfma_f32_16x16x32_bf16(al.v, wh0.v, acc0[mt], 0, 0, 0);
            acc1[mt] = __builtin_amdgcn_mfma_f32_16x16x32_bf16(ah.v, wh1.v, acc1[mt], 0, 0, 0);
            acc1[mt] = __builtin_amdgcn_mfma_f32_16x16x32_bf16(ah.v, wl1.v, acc1[mt], 0, 0, 0);
            acc1[mt] = __builtin_amdgcn_mfma_f32_16x16x32_bf16(al.v, wh1.v, acc1[mt], 0, 0, 0);
        }
    }

    // C/D layout (16x16, m89): col = lane&15 (= channel), row = quad*4 + reg (= token)
#pragma unroll
    for (int mt = 0; mt < 4; ++mt) {
        int token = mt * 16 + quad * 4;
#pragma unroll
        for (int r = 0; r < 4; ++r) {
            if constexpr (ATOMIC) {
                atomicAdd(&out[(size_t)(token + r) * OUTF + ch0], scale[ch0] * acc0[mt][r]);
                atomicAdd(&out[(size_t)(token + r) * OUTF + ch0 + 16], scale[ch0 + 16] * acc1[mt][r]);
            } else {
                part[((size_t)q * TOK + token + r) * OUTF + ch0]      = acc0[mt][r];
                part[((size_t)q * TOK + token + r) * OUTF + ch0 + 16] = acc1[mt][r];
            }
        }
    }
}

// ---------------------------------------------------------------------------
// k_post: out[t][o] = scale[o]*sum_q part[q][t][o] + sum_r tm[t][r]*B[o][r] + bias[o]
// ---------------------------------------------------------------------------
__global__ __launch_bounds__(256) void k_post(const float* __restrict__ part,
        const float* __restrict__ scale, const float* __restrict__ bias,
        const float* __restrict__ lB, const float* __restrict__ tm,
        float* __restrict__ out) {
    int o = blockIdx.x * 256 + threadIdx.x;
    int t = blockIdx.y;
    if (o >= OUTF) return;
    float s = 0.f;
#pragma unroll
    for (int qq = 0; qq < QCNT; ++qq)
        s += part[((size_t)qq * TOK + t) * OUTF + o];
    const float4* Br = (const float4*)(lB + (size_t)o * 16);
    const float4* tr = (const float4*)(tm + (size_t)t * 16);
    float l = 0.f;
#pragma unroll
    for (int i = 0; i < 4; ++i) {
        float4 b = Br[i], tt = tr[i];
        l += b.x * tt.x + b.y * tt.y + b.z * tt.z + b.w * tt.w;
    }
    out[(size_t)t * OUTF + o] = s * scale[o] + l + bias[o];
}

// Fallback pre-init for the atomic path: out = lora + bias, main adds scale*y.
__global__ __launch_bounds__(256) void k_pre(const float* __restrict__ bias,
        const float* __restrict__ lB, const float* __restrict__ tm,
        float* __restrict__ out) {
    int o = blockIdx.x * 256 + threadIdx.x;
    int t = blockIdx.y;
    if (o >= OUTF) return;
    const float4* Br = (const float4*)(lB + (size_t)o * 16);
    const float4* tr = (const float4*)(tm + (size_t)t * 16);
    float l = 0.f;
#pragma unroll
    for (int i = 0; i < 4; ++i) {
        float4 b = Br[i], tt = tr[i];
        l += b.x * tt.x + b.y * tt.y + b.z * tt.z + b.w * tt.w;
    }
    out[(size_t)t * OUTF + o] = l + bias[o];
}

extern "C" void kernel_launch(void* const* d_in, const int* in_sizes, int n_in,
                              void* d_out, int out_size, void* d_ws, size_t ws_size,
                              hipStream_t stream) {
    const float* x     = (const float*)d_in[0];
    const float* W     = (const float*)d_in[1];
    const float* scale = (const float*)d_in[2];
    const float* lA    = (const float*)d_in[3];
    const float* lB    = (const float*)d_in[4];
    const float* bias  = (const float*)d_in[5];
    float* out = (float*)d_out;

    char* ws = (char*)d_ws;
    unsigned short* xh = (unsigned short*)(ws);            // 512 KB
    unsigned short* xl = (unsigned short*)(ws + 524288);   // 512 KB
    float* tm   = (float*)(ws + 1048576);                  // 4 KB
    float* part = (float*)(ws + 1052672);                  // 45.1 MB
    const size_t need = 1052672 + (size_t)QCNT * TOK * OUTF * 4;  // ~46.1 MB

    k_prep_x<<<1024, 256, 0, stream>>>(x, xh, xl);
    k_lora_t<<<dim3(TOK, 4), 256, 0, stream>>>(x, lA, tm);

    if (ws_size >= need) {
        k_main<false><<<NBLK2 * QCNT, 256, 0, stream>>>(W, (const uint4*)xh,
                (const uint4*)xl, scale, part, out);
        k_post<<<dim3(43, TOK), 256, 0, stream>>>(part, scale, bias, lB, tm, out);
    } else {
        k_pre<<<dim3(43, TOK), 256, 0, stream>>>(bias, lB, tm, out);
        k_main<true><<<NBLK2 * QCNT, 256, 0, stream>>>(W, (const uint4*)xh,
                (const uint4*)xl, scale, nullptr, out);
    }
}

// Round 5
// 272.783 us; speedup vs baseline: 1.0953x; 1.0953x over previous
//
#include <hip/hip_runtime.h>
#include <hip/hip_bf16.h>
#include <cstdint>

// Problem constants
#define TOK   64
#define INF   4096
#define OUTF  11008
#define KCHUNKS 128      // INF / 32
#define QCNT  8          // split-K factor -> K_block = 512
#define NCHB  172        // OUTF / 64 channels per block

using bf16x8  = __attribute__((ext_vector_type(8))) __bf16;
using floatx4 = __attribute__((ext_vector_type(4))) float;

union B8u { uint32_t u[4]; uint4 q; bf16x8 v; };

// pack two fp32 into one dword of two truncated bf16 (elem a = low half)
__device__ __forceinline__ uint32_t hi2(float a, float b) {
    return (__float_as_uint(a) >> 16) | (__float_as_uint(b) & 0xffff0000u);
}
// residual after bf16 truncation (exact in fp32)
__device__ __forceinline__ float losub(float x) {
    return x - __uint_as_float(__float_as_uint(x) & 0xffff0000u);
}
__device__ __forceinline__ void packW(float4 a, float4 b, B8u& wh, B8u& wl) {
    wh.u[0] = hi2(a.x, a.y);  wh.u[1] = hi2(a.z, a.w);
    wh.u[2] = hi2(b.x, b.y);  wh.u[3] = hi2(b.z, b.w);
    wl.u[0] = hi2(losub(a.x), losub(a.y));
    wl.u[1] = hi2(losub(a.z), losub(a.w));
    wl.u[2] = hi2(losub(b.x), losub(b.y));
    wl.u[3] = hi2(losub(b.z), losub(b.w));
}

// ---------------------------------------------------------------------------
// k_prep_x: fp32 x[64][4096] -> bf16 hi/lo arrays in MFMA A-fragment order.
// uint4 index = (mt*128 + kc)*64 + lane ; elem j: x[mt*16+(lane&15)][kc*32+(lane>>4)*8+j]
// ---------------------------------------------------------------------------
__global__ __launch_bounds__(256) void k_prep_x(const float* __restrict__ x,
        unsigned short* __restrict__ xh, unsigned short* __restrict__ xl) {
    int idx  = blockIdx.x * 256 + threadIdx.x;          // 0..262143
    int j    = idx & 7;
    int lane = (idx >> 3) & 63;
    int kc   = (idx >> 9) & 127;
    int mt   = idx >> 16;
    int row  = mt * 16 + (lane & 15);
    int col  = kc * 32 + ((lane >> 4) << 3) + j;
    float v  = x[(size_t)row * INF + col];
    uint32_t u = __float_as_uint(v);
    float lo = losub(v);
    xh[idx] = (unsigned short)(u >> 16);
    xl[idx] = (unsigned short)(__float_as_uint(lo) >> 16);
}

// ---------------------------------------------------------------------------
// k_lora_t: tm[t][r] = sum_k x[t][k] * A[r][k].  grid (64 tokens, 4 rgroups),
// one wave per (t,r); fully unrolled -> independent loads in flight.
// ---------------------------------------------------------------------------
__global__ __launch_bounds__(256) void k_lora_t(const float* __restrict__ x,
        const float* __restrict__ A, float* __restrict__ tm) {
    int t = blockIdx.x, wv = threadIdx.x >> 6, lane = threadIdx.x & 63;
    int r = blockIdx.y * 4 + wv;
    const float4* xr = (const float4*)(x + (size_t)t * INF);
    const float4* ar = (const float4*)(A + (size_t)r * INF);
    float s = 0.f;
#pragma unroll
    for (int i = 0; i < INF / 4 / 64; ++i) {
        float4 a = xr[lane + i * 64], b = ar[lane + i * 64];
        s += a.x * b.x + a.y * b.y + a.z * b.z + a.w * b.w;
    }
#pragma unroll
    for (int off = 32; off > 0; off >>= 1) s += __shfl_down(s, off);
    if (lane == 0) tm[t * 16 + r] = s;
}

// ---------------------------------------------------------------------------
// k_main: y = x @ W^T via 16x16x32 bf16 MFMA, fp32 emulated hi/lo:
//   x*w ~= xh*wh + xh*wl + xl*wh
// KEY CHANGE vs R1-R4: W is DMA'd into LDS with global_load_lds using a
// per-row rotate swizzle. Every DMA instruction covers 8 FULL cache lines
// (2 rows x 512B dense) instead of the fragment-strided pattern (16 lines,
// 64B used each) that throttled the vmem transaction queue to ~2 TB/s.
// Fragment reads come from LDS (rotate-swizzled, ~2-way = free).
// Block = 64 channels x 64 tokens x K=512, 4 phases of k=128.
// ---------------------------------------------------------------------------
template<bool ATOMIC>
__global__ __launch_bounds__(256, 2) void k_main(const float* __restrict__ W,
        const uint4* __restrict__ xh, const uint4* __restrict__ xl,
        const float* __restrict__ scale, float* __restrict__ part,
        float* __restrict__ out) {
    // W slab: rows r=0..63 (channels), granules g=0..31 (16B each, k=128 floats)
    // slot (r,g) holds global k-granule f=(g-r)&31  -> reader uses g=(f+r)&31
    __shared__ uint4 wlds[2048];   // 32 KB
    __shared__ uint4 xsl[2048];    // 32 KB: [hl][mt][kc 0..3][lane]

    int tid  = threadIdx.x;
    int lane = tid & 63;
    int wv   = tid >> 6;
    int quad = lane >> 4;
    int nb   = blockIdx.x % NCHB;
    int q    = blockIdx.x / NCHB;        // 0..QCNT-1
    int chl  = wv * 16 + (lane & 15);    // local channel row (0..63)
    int ch   = nb * 64 + chl;

    const int kbase = q * 512;           // starting k (floats) for this block
    int rpar = lane >> 5;                // row parity within a W DMA issue
    int gg   = lane & 31;                // granule within row

    floatx4 acc[4] = {};

    for (int ph = 0; ph < 4; ++ph) {
        __syncthreads();   // previous phase's LDS reads complete before overwrite

        // ---- DMA W slab: 32 issues of 1KB, each = 2 rows x 512B dense ----
#pragma unroll
        for (int t = 0; t < 8; ++t) {
            int i = wv * 8 + t;          // issue 0..31
            int r = i * 2 + rpar;        // row 0..63
            int f = (gg - r) & 31;       // global granule (rotate swizzle)
            const float* src = W + (size_t)(nb * 64 + r) * INF
                             + kbase + ph * 128 + f * 4;
            __builtin_amdgcn_global_load_lds(
                (const __attribute__((address_space(1))) uint32_t*)src,
                (__attribute__((address_space(3))) uint32_t*)&wlds[i * 64],
                16, 0, 0);
        }
        // ---- DMA x slab: 32 issues of 1KB, contiguous in frag order ----
#pragma unroll
        for (int t = 0; t < 8; ++t) {
            int j  = wv * 8 + t;         // 0..31: [hl][mt][kc]
            int hl = j >> 4, mt = (j >> 2) & 3, kc = j & 3;
            const uint4* src = (hl ? xl : xh)
                + ((size_t)(mt * KCHUNKS + q * 16 + ph * 4 + kc) * 64 + lane);
            __builtin_amdgcn_global_load_lds(
                (const __attribute__((address_space(1))) uint32_t*)src,
                (__attribute__((address_space(3))) uint32_t*)&xsl[j * 64],
                16, 0, 0);
        }
        __syncthreads();   // slabs resident

        // ---- compute 4 chunks (k=32 each) ----
#pragma unroll
        for (int kc = 0; kc < 4; ++kc) {
            int f0 = (kc * 4 + quad) * 2;
            uint4 wf0 = wlds[chl * 32 + ((f0 + chl) & 31)];
            uint4 wf1 = wlds[chl * 32 + ((f0 + 1 + chl) & 31)];
            B8u wh, wl;
            packW(*(float4*)&wf0, *(float4*)&wf1, wh, wl);
#pragma unroll
            for (int mt = 0; mt < 4; ++mt) {
                B8u ah, al;
                ah.q = xsl[(mt * 4 + kc) * 64 + lane];
                al.q = xsl[(16 + mt * 4 + kc) * 64 + lane];
                acc[mt] = __builtin_amdgcn_mfma_f32_16x16x32_bf16(ah.v, wh.v, acc[mt], 0, 0, 0);
                acc[mt] = __builtin_amdgcn_mfma_f32_16x16x32_bf16(ah.v, wl.v, acc[mt], 0, 0, 0);
                acc[mt] = __builtin_amdgcn_mfma_f32_16x16x32_bf16(al.v, wh.v, acc[mt], 0, 0, 0);
            }
        }
    }

    // C/D layout (16x16, m89): col = lane&15 (= channel), row = quad*4 + reg (= token)
#pragma unroll
    for (int mt = 0; mt < 4; ++mt) {
        int token = mt * 16 + quad * 4;
#pragma unroll
        for (int r = 0; r < 4; ++r) {
            if constexpr (ATOMIC) {
                atomicAdd(&out[(size_t)(token + r) * OUTF + ch], scale[ch] * acc[mt][r]);
            } else {
                part[((size_t)q * TOK + token + r) * OUTF + ch] = acc[mt][r];
            }
        }
    }
}

// ---------------------------------------------------------------------------
// k_post: out[t][o] = scale[o]*sum_q part[q][t][o] + sum_r tm[t][r]*B[o][r] + bias[o]
// ---------------------------------------------------------------------------
__global__ __launch_bounds__(256) void k_post(const float* __restrict__ part,
        const float* __restrict__ scale, const float* __restrict__ bias,
        const float* __restrict__ lB, const float* __restrict__ tm,
        float* __restrict__ out) {
    int o = blockIdx.x * 256 + threadIdx.x;
    int t = blockIdx.y;
    if (o >= OUTF) return;
    float s = 0.f;
#pragma unroll
    for (int qq = 0; qq < QCNT; ++qq)
        s += part[((size_t)qq * TOK + t) * OUTF + o];
    const float4* Br = (const float4*)(lB + (size_t)o * 16);
    const float4* tr = (const float4*)(tm + (size_t)t * 16);
    float l = 0.f;
#pragma unroll
    for (int i = 0; i < 4; ++i) {
        float4 b = Br[i], tt = tr[i];
        l += b.x * tt.x + b.y * tt.y + b.z * tt.z + b.w * tt.w;
    }
    out[(size_t)t * OUTF + o] = s * scale[o] + l + bias[o];
}

// Fallback pre-init for the atomic path: out = lora + bias, main adds scale*y.
__global__ __launch_bounds__(256) void k_pre(const float* __restrict__ bias,
        const float* __restrict__ lB, const float* __restrict__ tm,
        float* __restrict__ out) {
    int o = blockIdx.x * 256 + threadIdx.x;
    int t = blockIdx.y;
    if (o >= OUTF) return;
    const float4* Br = (const float4*)(lB + (size_t)o * 16);
    const float4* tr = (const float4*)(tm + (size_t)t * 16);
    float l = 0.f;
#pragma unroll
    for (int i = 0; i < 4; ++i) {
        float4 b = Br[i], tt = tr[i];
        l += b.x * tt.x + b.y * tt.y + b.z * tt.z + b.w * tt.w;
    }
    out[(size_t)t * OUTF + o] = l + bias[o];
}

extern "C" void kernel_launch(void* const* d_in, const int* in_sizes, int n_in,
                              void* d_out, int out_size, void* d_ws, size_t ws_size,
                              hipStream_t stream) {
    const float* x     = (const float*)d_in[0];
    const float* W     = (const float*)d_in[1];
    const float* scale = (const float*)d_in[2];
    const float* lA    = (const float*)d_in[3];
    const float* lB    = (const float*)d_in[4];
    const float* bias  = (const float*)d_in[5];
    float* out = (float*)d_out;

    char* ws = (char*)d_ws;
    unsigned short* xh = (unsigned short*)(ws);            // 512 KB
    unsigned short* xl = (unsigned short*)(ws + 524288);   // 512 KB
    float* tm   = (float*)(ws + 1048576);                  // 4 KB
    float* part = (float*)(ws + 1052672);                  // 22.5 MB
    const size_t need = 1052672 + (size_t)QCNT * TOK * OUTF * 4;  // ~23.6 MB

    k_prep_x<<<1024, 256, 0, stream>>>(x, xh, xl);
    k_lora_t<<<dim3(TOK, 4), 256, 0, stream>>>(x, lA, tm);

    if (ws_size >= need) {
        k_main<false><<<NCHB * QCNT, 256, 0, stream>>>(W, (const uint4*)xh,
                (const uint4*)xl, scale, part, out);
        k_post<<<dim3(43, TOK), 256, 0, stream>>>(part, scale, bias, lB, tm, out);
    } else {
        k_pre<<<dim3(43, TOK), 256, 0, stream>>>(bias, lB, tm, out);
        k_main<true><<<NCHB * QCNT, 256, 0, stream>>>(W, (const uint4*)xh,
                (const uint4*)xl, scale, nullptr, out);
    }
}